// Round 1
// baseline (742.882 us; speedup 1.0000x reference)
//
#include <hip/hip_runtime.h>
#include <cstdint>
#include <cstddef>

#define B_ 8
#define N_ 2048
#define D_ 2048
#define E_ 64
#define CAP_ 64
#define NTOK (B_*N_)                  // 16384 tokens
#define GEMM_BLOCKS 256               // 64 tokens per block
#define ZERO_BLOCKS 1792
#define DK 128                        // D-tile staged in LDS
#define MASK_ELEMS ((size_t)NTOK*(size_t)E_*(size_t)CAP_)   // 67108864 per output

// K1: fused zero-fill of the two big outputs + logits GEMM + per-token softmax stats.
// lane = expert; each wave owns 16 tokens; token values fetched via wave-uniform
// (readfirstlane'd) addresses -> scalar loads; W tile staged in LDS.
__global__ __launch_bounds__(256)
void k_gemm_zero(const float* __restrict__ X, const float* __restrict__ W,
                 float* __restrict__ out, float* __restrict__ gate_ws,
                 int* __restrict__ idx_ws, float* __restrict__ z_ws) {
  const int bid = blockIdx.x;
  if (bid >= GEMM_BLOCKS) {
    // ---- zero-fill blocks: clear dispatch_mask + combine_array (+ z slot) ----
    const int zb = bid - GEMM_BLOCKS;
    float4* o4 = (float4*)out;
    const size_t total4 = (2*MASK_ELEMS) / 4;     // 33554432 float4s
    const size_t stride = (size_t)ZERO_BLOCKS * 256;
    for (size_t i = (size_t)zb*256 + threadIdx.x; i < total4; i += stride)
      o4[i] = make_float4(0.f, 0.f, 0.f, 0.f);
    if (zb == 0 && threadIdx.x == 0) out[2*MASK_ELEMS] = 0.f;  // z-loss slot
    return;
  }

  __shared__ float Ws[DK][E_];   // 32 KiB
  const int tid  = threadIdx.x;
  const int lane = tid & 63;                                   // = expert
  const int wv   = __builtin_amdgcn_readfirstlane(tid >> 6);   // wave id (uniform)
  const int tokbase = bid*64 + wv*16;
  const float* xp = X + (size_t)tokbase * D_;                  // wave-uniform base

  float acc[16];
  #pragma unroll
  for (int i = 0; i < 16; ++i) acc[i] = 0.f;

  for (int d0 = 0; d0 < D_; d0 += DK) {
    __syncthreads();
    // stage W[d0..d0+DK) x [64] into LDS, coalesced float4
    {
      const float4* wg = (const float4*)(W + (size_t)d0 * E_);
      float4* wsv = (float4*)&Ws[0][0];
      #pragma unroll
      for (int p = 0; p < (DK*E_/4)/256; ++p)
        wsv[p*256 + tid] = wg[p*256 + tid];
    }
    __syncthreads();

    #pragma unroll 4
    for (int dq = 0; dq < DK/4; ++dq) {
      const float w0 = Ws[dq*4+0][lane];
      const float w1 = Ws[dq*4+1][lane];
      const float w2 = Ws[dq*4+2][lane];
      const float w3 = Ws[dq*4+3][lane];
      #pragma unroll
      for (int i = 0; i < 16; ++i) {
        const float4 x = *(const float4*)(xp + (size_t)i*D_ + d0 + dq*4); // uniform -> s_load
        float a = acc[i];
        a = fmaf(x.x, w0, a);
        a = fmaf(x.y, w1, a);
        a = fmaf(x.z, w2, a);
        a = fmaf(x.w, w3, a);
        acc[i] = a;
      }
    }
  }

  // ---- per-token reductions over the 64 lanes (lane = expert) ----
  #pragma unroll 1
  for (int i = 0; i < 16; ++i) {
    float vmax = acc[i];
    int   vidx = lane;
    #pragma unroll
    for (int m = 1; m < 64; m <<= 1) {
      const float om = __shfl_xor(vmax, m);
      const int   oi = __shfl_xor(vidx, m);
      if (om > vmax || (om == vmax && oi < vidx)) { vmax = om; vidx = oi; }
    }
    float se = expf(acc[i] - vmax);
    #pragma unroll
    for (int m = 1; m < 64; m <<= 1) se += __shfl_xor(se, m);
    if (lane == 0) {
      const int row = tokbase + i;
      gate_ws[row] = 1.0f / se;          // max softmax prob = exp(m-m)/se
      idx_ws[row]  = vidx;               // first-occurrence argmax
      z_ws[row]    = vmax + logf(se);    // logsumexp
    }
  }
}

// K2: per-batch position-in-expert cumsum via bit-sliced ballots + scatter + z-loss.
__global__ __launch_bounds__(64)
void k_route(const float* __restrict__ gate_ws, const int* __restrict__ idx_ws,
             const float* __restrict__ z_ws, float* __restrict__ out) {
  const int b    = blockIdx.x;
  const int lane = threadIdx.x;
  float* dispatch = out;
  float* combine  = out + MASK_ELEMS;

  int   cnt  = 0;     // running count for expert == lane
  float zsum = 0.f;
  const unsigned long long below = (1ULL << lane) - 1ULL;

  for (int n0 = 0; n0 < N_; n0 += 64) {
    const int   t    = b*N_ + n0 + lane;
    const int   idx  = idx_ws[t];
    const float gate = gate_ws[t];
    const float z    = z_ws[t];
    zsum += z * z;

    unsigned long long bb[6];
    #pragma unroll
    for (int k = 0; k < 6; ++k) bb[k] = __ballot((idx >> k) & 1);

    unsigned long long m_tok = ~0ULL;   // lanes whose token picked MY token's expert
    unsigned long long m_exp = ~0ULL;   // lanes whose token picked expert == my lane
    #pragma unroll
    for (int k = 0; k < 6; ++k) {
      m_tok &= ((idx  >> k) & 1) ? bb[k] : ~bb[k];
      m_exp &= ((lane >> k) & 1) ? bb[k] : ~bb[k];
    }

    const int rank = __popcll(m_tok & below);     // same-expert predecessors in chunk
    const int base = __shfl(cnt, idx);            // running count from owner lane
    const int pos  = base + rank;
    cnt += __popcll(m_exp);                       // update my expert's running count

    if (pos < CAP_) {
      const size_t o = (((size_t)t)*E_ + (size_t)idx)*CAP_ + (size_t)pos;
      dispatch[o] = 1.0f;
      combine[o]  = gate;
    }
  }

  #pragma unroll
  for (int m = 1; m < 64; m <<= 1) zsum += __shfl_xor(zsum, m);
  if (lane == 0) atomicAdd(out + 2*MASK_ELEMS, zsum * (1.0f / (float)NTOK));
}

extern "C" void kernel_launch(void* const* d_in, const int* in_sizes, int n_in,
                              void* d_out, int out_size, void* d_ws, size_t ws_size,
                              hipStream_t stream) {
  const float* X = (const float*)d_in[0];   // [8,2048,2048]
  const float* W = (const float*)d_in[1];   // [2048,64]
  float* out = (float*)d_out;               // dispatch | combine | z_loss

  float* gate_ws = (float*)d_ws;
  int*   idx_ws  = (int*)  ((char*)d_ws + 65536);
  float* z_ws    = (float*)((char*)d_ws + 131072);

  hipLaunchKernelGGL(k_gemm_zero, dim3(GEMM_BLOCKS + ZERO_BLOCKS), dim3(256), 0, stream,
                     X, W, out, gate_ws, idx_ws, z_ws);
  hipLaunchKernelGGL(k_route, dim3(B_), dim3(64), 0, stream,
                     gate_ws, idx_ws, z_ws, out);
}

// Round 2
// 310.168 us; speedup vs baseline: 2.3951x; 2.3951x over previous
//
#include <hip/hip_runtime.h>
#include <cstdint>
#include <cstddef>

#define B_ 8
#define N_ 2048
#define D_ 2048
#define E_ 64
#define CAP_ 64
#define NTOK (B_*N_)                  // 16384 tokens
#define GEMM_BLOCKS 256               // 64 tokens per block (4 waves x 16 tokens)
#define ZERO_BLOCKS 1792
#define MASK_ELEMS ((size_t)NTOK*(size_t)E_*(size_t)CAP_)   // 67108864 per output

typedef float f32x4 __attribute__((ext_vector_type(4)));

// K1: fused zero-fill of the two big outputs + logits GEMM + per-token softmax stats.
// GEMM: lane = expert for FMA/reduction; X fetched with per-lane vector loads
// (lane = (token, d-quad)) and broadcast via v_readlane -> SGPR fma operand.
// No LDS, no barriers: waves are fully independent and deep-pipelined.
__global__ __launch_bounds__(256)
void k_gemm_zero(const float* __restrict__ X, const float* __restrict__ W,
                 float* __restrict__ out, float* __restrict__ gate_ws,
                 int* __restrict__ idx_ws, float* __restrict__ z_ws) {
  const int bid = blockIdx.x;
  if (bid >= GEMM_BLOCKS) {
    // ---- zero-fill blocks: clear dispatch_mask + combine_array (+ z slot) ----
    const int zb = bid - GEMM_BLOCKS;
    f32x4* o4 = (f32x4*)out;
    const size_t total4 = (2*MASK_ELEMS) / 4;     // 33554432 f32x4s
    const size_t stride = (size_t)ZERO_BLOCKS * 256;
    const f32x4 z4 = {0.f, 0.f, 0.f, 0.f};
    for (size_t i = (size_t)zb*256 + threadIdx.x; i < total4; i += stride)
      __builtin_nontemporal_store(z4, &o4[i]);
    if (zb == 0 && threadIdx.x == 0) out[2*MASK_ELEMS] = 0.f;  // z-loss slot
    return;
  }

  const int tid  = threadIdx.x;
  const int lane = tid & 63;                                   // = expert for FMA
  const int wid  = __builtin_amdgcn_readfirstlane(tid >> 6);   // wave id (uniform)
  const int tokbase = bid*64 + wid*16;

  // X load layout: lane = 4*token + quad; one dwordx4 load = 16 tokens x 16 d.
  const int tL = lane >> 2;
  const int q  = lane & 3;
  const float* xlane = X + (size_t)(tokbase + tL)*D_ + q*4;
  const float* wlane = W + lane;                                // lane = expert

  float acc[16];
  #pragma unroll
  for (int i = 0; i < 16; ++i) acc[i] = 0.f;

  // prefetch chunk 0
  f32x4 xv = __builtin_nontemporal_load((const f32x4*)xlane);
  float wreg[16];
  #pragma unroll
  for (int k = 0; k < 16; ++k) wreg[k] = wlane[(size_t)k * E_];

  for (int d0 = 0; d0 < D_; d0 += 16) {
    // prefetch next 16-d chunk (wraps to 0 on the last iter: valid, discarded)
    const int d1 = (d0 + 16 < D_) ? (d0 + 16) : 0;
    f32x4 xn = __builtin_nontemporal_load((const f32x4*)(xlane + d1));
    float wn[16];
    #pragma unroll
    for (int k = 0; k < 16; ++k) wn[k] = wlane[(size_t)(d1 + k) * E_];

    // consume current chunk: d = d0 + k lives in lane 4i + (k>>2), comp (k&3)
    #pragma unroll
    for (int k = 0; k < 16; ++k) {
      const float wk  = wreg[k];
      const int srcq  = k >> 2;
      const int c     = k & 3;
      #pragma unroll
      for (int i = 0; i < 16; ++i) {
        const float xs = __int_as_float(
            __builtin_amdgcn_readlane(__float_as_int(xv[c]), i*4 + srcq));
        acc[i] = fmaf(xs, wk, acc[i]);
      }
    }
    xv = xn;
    #pragma unroll
    for (int k = 0; k < 16; ++k) wreg[k] = wn[k];
  }

  // ---- per-token reductions over the 64 lanes (lane = expert) ----
  #pragma unroll 1
  for (int i = 0; i < 16; ++i) {
    float vmax = acc[i];
    int   vidx = lane;
    #pragma unroll
    for (int m = 1; m < 64; m <<= 1) {
      const float om = __shfl_xor(vmax, m);
      const int   oi = __shfl_xor(vidx, m);
      if (om > vmax || (om == vmax && oi < vidx)) { vmax = om; vidx = oi; }
    }
    float se = expf(acc[i] - vmax);
    #pragma unroll
    for (int m = 1; m < 64; m <<= 1) se += __shfl_xor(se, m);
    if (lane == 0) {
      const int row = tokbase + i;
      gate_ws[row] = 1.0f / se;          // max softmax prob = exp(m-m)/se
      idx_ws[row]  = vidx;               // first-occurrence argmax
      z_ws[row]    = vmax + logf(se);    // logsumexp
    }
  }
}

// K2: per-batch position-in-expert cumsum via bit-sliced ballots + scatter + z-loss.
__global__ __launch_bounds__(64)
void k_route(const float* __restrict__ gate_ws, const int* __restrict__ idx_ws,
             const float* __restrict__ z_ws, float* __restrict__ out) {
  const int b    = blockIdx.x;
  const int lane = threadIdx.x;
  float* dispatch = out;
  float* combine  = out + MASK_ELEMS;

  int   cnt  = 0;     // running count for expert == lane
  float zsum = 0.f;
  const unsigned long long below = (1ULL << lane) - 1ULL;

  for (int n0 = 0; n0 < N_; n0 += 64) {
    const int   t    = b*N_ + n0 + lane;
    const int   idx  = idx_ws[t];
    const float gate = gate_ws[t];
    const float z    = z_ws[t];
    zsum += z * z;

    unsigned long long bb[6];
    #pragma unroll
    for (int k = 0; k < 6; ++k) bb[k] = __ballot((idx >> k) & 1);

    unsigned long long m_tok = ~0ULL;   // lanes whose token picked MY token's expert
    unsigned long long m_exp = ~0ULL;   // lanes whose token picked expert == my lane
    #pragma unroll
    for (int k = 0; k < 6; ++k) {
      m_tok &= ((idx  >> k) & 1) ? bb[k] : ~bb[k];
      m_exp &= ((lane >> k) & 1) ? bb[k] : ~bb[k];
    }

    const int rank = __popcll(m_tok & below);     // same-expert predecessors in chunk
    const int base = __shfl(cnt, idx);            // running count from owner lane
    const int pos  = base + rank;
    cnt += __popcll(m_exp);                       // update my expert's running count

    if (pos < CAP_) {
      const size_t o = (((size_t)t)*E_ + (size_t)idx)*CAP_ + (size_t)pos;
      dispatch[o] = 1.0f;
      combine[o]  = gate;
    }
  }

  #pragma unroll
  for (int m = 1; m < 64; m <<= 1) zsum += __shfl_xor(zsum, m);
  if (lane == 0) atomicAdd(out + 2*MASK_ELEMS, zsum * (1.0f / (float)NTOK));
}

extern "C" void kernel_launch(void* const* d_in, const int* in_sizes, int n_in,
                              void* d_out, int out_size, void* d_ws, size_t ws_size,
                              hipStream_t stream) {
  const float* X = (const float*)d_in[0];   // [8,2048,2048]
  const float* W = (const float*)d_in[1];   // [2048,64]
  float* out = (float*)d_out;               // dispatch | combine | z_loss

  float* gate_ws = (float*)d_ws;
  int*   idx_ws  = (int*)  ((char*)d_ws + 65536);
  float* z_ws    = (float*)((char*)d_ws + 131072);

  hipLaunchKernelGGL(k_gemm_zero, dim3(GEMM_BLOCKS + ZERO_BLOCKS), dim3(256), 0, stream,
                     X, W, out, gate_ws, idx_ws, z_ws);
  hipLaunchKernelGGL(k_route, dim3(B_), dim3(64), 0, stream,
                     gate_ws, idx_ws, z_ws, out);
}

// Round 3
// 260.077 us; speedup vs baseline: 2.8564x; 1.1926x over previous
//
#include <hip/hip_runtime.h>
#include <cstdint>
#include <cstddef>

#define B_ 8
#define N_ 2048
#define D_ 2048
#define E_ 64
#define CAP_ 64
#define NTOK (B_*N_)                  // 16384 tokens
#define GEMM_BLOCKS 256               // 64 tokens/block; 4 waves K-split D by 512
#define ZERO_BLOCKS 1792
#define MASK_ELEMS ((size_t)NTOK*(size_t)E_*(size_t)CAP_)   // 67108864 per output

typedef float f32x4 __attribute__((ext_vector_type(4)));

// K1: fused zero-fill + logits GEMM + per-token softmax stats.
// GEMM: lane = token, acc[64] = this token's 64 expert logits.
// W rows fetched via wave-uniform addresses -> s_load -> free SGPR fma operand.
// X streamed per-lane with dwordx4 (deep vmcnt pipeline). K-split over 4 waves,
// combined in padded LDS (bank = (tok+e)%32, conflict-free).
__global__ __launch_bounds__(256)
void k_gemm_zero(const float* __restrict__ X, const float* __restrict__ W,
                 float* __restrict__ out, float* __restrict__ gate_ws,
                 int* __restrict__ idx_ws, float* __restrict__ z_ws) {
  const int bid = blockIdx.x;
  if (bid >= GEMM_BLOCKS) {
    // ---- zero-fill blocks: clear dispatch_mask + combine_array (+ z slot) ----
    const int zb = bid - GEMM_BLOCKS;
    f32x4* o4 = (f32x4*)out;
    const size_t total4 = (2*MASK_ELEMS) / 4;     // 33554432 f32x4s
    const size_t stride = (size_t)ZERO_BLOCKS * 256;
    const f32x4 z4 = {0.f, 0.f, 0.f, 0.f};
    for (size_t i = (size_t)zb*256 + threadIdx.x; i < total4; i += stride)
      __builtin_nontemporal_store(z4, &o4[i]);
    if (zb == 0 && threadIdx.x == 0) out[2*MASK_ELEMS] = 0.f;  // z-loss slot
    return;
  }

  __shared__ float L[64][65];   // logits accumulator, padded
  const int tid  = threadIdx.x;
  const int lane = tid & 63;                                   // = token within block
  const int wid  = __builtin_amdgcn_readfirstlane(tid >> 6);   // wave id (uniform!)
  const int tok  = bid*64 + lane;

  for (int i = tid; i < 64*65; i += 256) ((float*)L)[i] = 0.f;
  __syncthreads();

  float acc[64];
  #pragma unroll
  for (int e = 0; e < 64; ++e) acc[e] = 0.f;

  const float* xrow  = X + (size_t)tok * D_ + wid*512;         // per-lane stream
  const float* wbase = W + (size_t)(wid*512) * E_;             // wave-uniform

  // software-pipelined: prefetch next 8-d chunk of X while consuming current
  f32x4 xa = *(const f32x4*)(xrow + 0);
  f32x4 xb = *(const f32x4*)(xrow + 4);
  for (int dc = 0; dc < 512; dc += 8) {
    const int dn = (dc + 8 < 512) ? dc + 8 : 0;
    f32x4 na = *(const f32x4*)(xrow + dn);
    f32x4 nb = *(const f32x4*)(xrow + dn + 4);
    #pragma unroll
    for (int k = 0; k < 8; ++k) {
      const float xk = (k < 4) ? xa[k] : xb[k - 4];
      const float* wr = wbase + (size_t)(dc + k) * E_;         // uniform -> s_load
      #pragma unroll
      for (int e = 0; e < 64; ++e)
        acc[e] = fmaf(xk, wr[e], acc[e]);                      // v_fma v,s,v
    }
    xa = na; xb = nb;
  }

  // ---- combine K-split partials (conflict-free LDS atomics) ----
  #pragma unroll
  for (int e = 0; e < 64; ++e)
    atomicAdd(&L[lane][e], acc[e]);
  __syncthreads();

  // ---- per-token softmax stats: wave 0, lane = token, serial over 64 experts ----
  if (wid == 0) {
    float m = -3.4e38f; int mi = 0;
    #pragma unroll 1
    for (int e = 0; e < 64; ++e) {
      const float v = L[lane][e];
      if (v > m) { m = v; mi = e; }         // strict > keeps first index on ties
    }
    float s = 0.f;
    #pragma unroll 1
    for (int e = 0; e < 64; ++e) s += expf(L[lane][e] - m);
    gate_ws[tok] = 1.0f / s;                // max softmax prob
    idx_ws[tok]  = mi;                      // argmax (first occurrence)
    z_ws[tok]    = m + logf(s);             // logsumexp
  }
}

// K2: per-batch position-in-expert cumsum via bit-sliced ballots + scatter + z-loss.
__global__ __launch_bounds__(64)
void k_route(const float* __restrict__ gate_ws, const int* __restrict__ idx_ws,
             const float* __restrict__ z_ws, float* __restrict__ out) {
  const int b    = blockIdx.x;
  const int lane = threadIdx.x;
  float* dispatch = out;
  float* combine  = out + MASK_ELEMS;

  int   cnt  = 0;     // running count for expert == lane
  float zsum = 0.f;
  const unsigned long long below = (1ULL << lane) - 1ULL;

  for (int n0 = 0; n0 < N_; n0 += 64) {
    const int   t    = b*N_ + n0 + lane;
    const int   idx  = idx_ws[t];
    const float gate = gate_ws[t];
    const float z    = z_ws[t];
    zsum += z * z;

    unsigned long long bb[6];
    #pragma unroll
    for (int k = 0; k < 6; ++k) bb[k] = __ballot((idx >> k) & 1);

    unsigned long long m_tok = ~0ULL;   // lanes whose token picked MY token's expert
    unsigned long long m_exp = ~0ULL;   // lanes whose token picked expert == my lane
    #pragma unroll
    for (int k = 0; k < 6; ++k) {
      m_tok &= ((idx  >> k) & 1) ? bb[k] : ~bb[k];
      m_exp &= ((lane >> k) & 1) ? bb[k] : ~bb[k];
    }

    const int rank = __popcll(m_tok & below);     // same-expert predecessors in chunk
    const int base = __shfl(cnt, idx);            // running count from owner lane
    const int pos  = base + rank;
    cnt += __popcll(m_exp);                       // update my expert's running count

    if (pos < CAP_) {
      const size_t o = (((size_t)t)*E_ + (size_t)idx)*CAP_ + (size_t)pos;
      dispatch[o] = 1.0f;
      combine[o]  = gate;
    }
  }

  #pragma unroll
  for (int m = 1; m < 64; m <<= 1) zsum += __shfl_xor(zsum, m);
  if (lane == 0) atomicAdd(out + 2*MASK_ELEMS, zsum * (1.0f / (float)NTOK));
}

extern "C" void kernel_launch(void* const* d_in, const int* in_sizes, int n_in,
                              void* d_out, int out_size, void* d_ws, size_t ws_size,
                              hipStream_t stream) {
  const float* X = (const float*)d_in[0];   // [8,2048,2048]
  const float* W = (const float*)d_in[1];   // [2048,64]
  float* out = (float*)d_out;               // dispatch | combine | z_loss

  float* gate_ws = (float*)d_ws;
  int*   idx_ws  = (int*)  ((char*)d_ws + 65536);
  float* z_ws    = (float*)((char*)d_ws + 131072);

  hipLaunchKernelGGL(k_gemm_zero, dim3(GEMM_BLOCKS + ZERO_BLOCKS), dim3(256), 0, stream,
                     X, W, out, gate_ws, idx_ws, z_ws);
  hipLaunchKernelGGL(k_route, dim3(B_), dim3(64), 0, stream,
                     gate_ws, idx_ws, z_ws, out);
}